// Round 6
// baseline (204.881 us; speedup 1.0000x reference)
//
#include <hip/hip_runtime.h>

// Problem constants (match reference setup_inputs()).
#define Bv 8
#define Nv 2048
#define Dv 8
#define Cv 128
#define Fv 256
#define Tv 4

#define CC   32                // c per walk block
#define HALO 16                // 4 steps * max offset 4

// Fused T-step walk. Each block: one b, a TILE_-wide owned n range (+16 halo
// each side = LN_ loaded), a 32-wide c chunk. Each thread: ONE n-slot
// (nl=tid>>3), a float4 of c (ci4=tid&7), all 8 d in registers. Post-coin
// exchange via LDS with ds_*_b128 on both sides. LDS rows are 32 floats = one
// full bank line, so every access covers all 32 banks at the b128 structural
// minimum -> conflict-free regardless of gather divergence.
// Valid region after step t is [4t, LN_-4t); owned region [16, 16+TILE_) is
// exactly the T=4 dependence cone, so halo-edge wrap garbage never reaches
// the output. Tail-tile overlap (TILE_=96: 22*96>2048) rewrites identical
// values computed from identical inputs -> benign.
template<int TILE_, int LN_, int NTILES_>
__global__ __launch_bounds__(LN_ * 8, 4)
void walk_kernel(const float* __restrict__ amps0,
                 const float* __restrict__ coins,
                 const int* __restrict__ swap_a,
                 const int* __restrict__ swap_b,
                 float* __restrict__ dsum)
{
    extern __shared__ float abuf[];        // [n_local][d][c] = LN_*8*32 floats

    const int bid  = blockIdx.x;
    const int b    = bid / (NTILES_ * 4);
    const int rem  = bid - b * (NTILES_ * 4);
    const int tile = rem >> 2;             // 0..NTILES_-1
    const int c0   = (rem & 3) * CC;       // 4 c-chunks

    const int tid = threadIdx.x;
    const int ci4 = tid & 7;               // c-lane: c = c0 + ci4*4 + 0..3
    const int nl  = tid >> 3;              // 0..LN_-1 local n slot

    const int n_load_start = tile * TILE_ - HALO;   // may be negative (mod N)
    const int ng = (n_load_start + nl) & (Nv - 1);  // global n of this slot

    float4 amp[Dv];     // per-thread amplitude state (8 d x 4 c)
    int    idx[Dv];     // packed LDS gather offsets (t-invariant, float index)

    // ---- load initial amplitudes (float4, coalesced) ----
    {
        const float* srcf = amps0 + ((size_t)(b * Nv + ng) * Dv) * Cv + c0 + ci4 * 4;
        #pragma unroll
        for (int dd = 0; dd < Dv; ++dd)
            amp[dd] = *reinterpret_cast<const float4*>(srcf + (size_t)dd * Cv);
    }

    // ---- precompute gather offsets (t-invariant) ----
    {
        const int* pa = swap_a + (size_t)(b * Nv + ng) * Dv;
        const int* pb = swap_b + (size_t)(b * Nv + ng) * Dv;
        #pragma unroll
        for (int dd = 0; dd < Dv; ++dd) {
            const int sa = pa[dd];
            const int sb = pb[dd];
            // local slot of source n; &(LN_-1) exact for in-window sources
            // (LN_ | 2048); halo-edge wraps give in-range garbage only.
            const int sl = (sa - n_load_start + Nv) & (LN_ - 1);
            idx[dd] = (sl * Dv + sb) * CC + ci4 * 4;
        }
    }

    for (int t = 0; t < Tv; ++t) {
        const float* cm = coins + t * Dv * Dv;   // wave-uniform addresses
        float4 a[Dv];

        // Structured-coin check: cm == wd*I + wo*(J-I)? (true for Grover
        // diffusion: wo=2/D exact, wd=-1+2/D exact in fp32). Wave-uniform ->
        // scalar branch. Generic fallback keeps correctness for any coins.
        const float wd = cm[0];
        const float wo = cm[1];
        bool uni = true;
        #pragma unroll
        for (int i = 0; i < Dv; ++i)
            #pragma unroll
            for (int j = 0; j < Dv; ++j)
                uni = uni && (cm[i * Dv + j] == ((i == j) ? wd : wo));

        if (uni) {
            // a[e] = wo * sum_d amp[d] + (wd - wo) * amp[e]
            const float dw = wd - wo;
            float4 s = amp[0];
            #pragma unroll
            for (int dd = 1; dd < Dv; ++dd) {
                s.x += amp[dd].x; s.y += amp[dd].y;
                s.z += amp[dd].z; s.w += amp[dd].w;
            }
            #pragma unroll
            for (int e = 0; e < Dv; ++e) {
                a[e].x = wo * s.x + dw * amp[e].x;
                a[e].y = wo * s.y + dw * amp[e].y;
                a[e].z = wo * s.z + dw * amp[e].z;
                a[e].w = wo * s.w + dw * amp[e].w;
            }
        } else {
            // generic: a[e] = sum_d amp[d] * cm[d][e]
            #pragma unroll
            for (int e = 0; e < Dv; ++e) { a[e].x = a[e].y = a[e].z = a[e].w = 0.f; }
            #pragma unroll
            for (int dd = 0; dd < Dv; ++dd) {
                #pragma unroll
                for (int e = 0; e < Dv; ++e) {
                    const float w = cm[dd * Dv + e];
                    a[e].x += amp[dd].x * w;
                    a[e].y += amp[dd].y * w;
                    a[e].z += amp[dd].z * w;
                    a[e].w += amp[dd].w * w;
                }
            }
        }

        // publish to LDS: 8 x ds_write_b128, conflict-free
        {
            float* base = abuf + nl * (Dv * CC) + ci4 * 4;
            #pragma unroll
            for (int e = 0; e < Dv; ++e)
                *reinterpret_cast<float4*>(base + e * CC) = a[e];
        }
        __syncthreads();
        // shift step: 8 x ds_read_b128 gather
        #pragma unroll
        for (int dd = 0; dd < Dv; ++dd)
            amp[dd] = *reinterpret_cast<const float4*>(&abuf[idx[dd]]);
        __syncthreads();
    }

    // d[b,n,c] = sum_d amps^2 for owned region only (float4 store)
    if (nl >= HALO && nl < HALO + TILE_) {
        float4 s;
        s.x = s.y = s.z = s.w = 0.f;
        #pragma unroll
        for (int dd = 0; dd < Dv; ++dd) {
            s.x += amp[dd].x * amp[dd].x;
            s.y += amp[dd].y * amp[dd].y;
            s.z += amp[dd].z * amp[dd].z;
            s.w += amp[dd].w * amp[dd].w;
        }
        *reinterpret_cast<float4*>(dsum + (size_t)(b * Nv + ng) * Cv + c0 + ci4 * 4) = s;
    }
}

// big: TILE=96, LN=128, 22 tiles, 1024 thr, 128 KB LDS (needs opt-in)
// small: TILE=32, LN=64, 64 tiles, 512 thr, 64 KB LDS (no opt-in needed)
constexpr int BIG_TILE = 96,  BIG_LN = 128, BIG_NT = 22;
constexpr int SM_TILE  = 32,  SM_LN  = 64,  SM_NT  = 64;
constexpr size_t BIG_LDS = (size_t)BIG_LN * Dv * CC * 4;   // 131072
constexpr size_t SM_LDS  = (size_t)SM_LN  * Dv * CC * 4;   // 65536

// ---- quant config ----
#define CQ    32                 // c per block
#define NCH   128                // n per block -> 512 blocks
#define NPART (Nv / NCH)         // 16 n-chunks
constexpr size_t OUT_FLOATS  = (size_t)Bv * Cv * Fv;       // 262144 (1 MiB)
constexpr size_t DSUM_BYTES  = (size_t)Bv * Nv * Cv * 4;   // 8 MiB
constexpr size_t PART_BYTES  = (size_t)NPART * OUT_FLOATS * 4; // 16 MiB

typedef float v2f __attribute__((ext_vector_type(2)));

// out[b,c,f] = sum_n d[b,n,c] * neibs[b,n,f]
// threads = f (256, coalesced); d reads are block-uniform (scalarizable to
// s_load); inner accumulate on float2 vectors to invite v_pk_fma_f32
// (identical per-output fp order either way). n split 16-way; finish either
// via atomics onto zeroed out (ATOMIC=true) or disjoint per-chunk partial
// buffers reduced by reduce_kernel (ATOMIC=false, no atomics at all).
template<bool ATOMIC>
__global__ __launch_bounds__(256)
void quant_kernel(const float* __restrict__ dsum,
                  const float* __restrict__ neibs,
                  float* __restrict__ dst)   // out (ATOMIC) / partials base
{
    const int bid = blockIdx.x;
    const int b   = bid >> 6;          // 64 blocks per batch
    const int cq  = (bid >> 4) & 3;    // 4 c-chunks
    const int nc  = bid & 15;          // 16 n-chunks
    const int c0  = cq * CQ;
    const int n0  = nc * NCH;
    const int f   = threadIdx.x;       // 0..255

    v2f acc2[CQ / 2];
    #pragma unroll
    for (int k = 0; k < CQ / 2; ++k) acc2[k] = (v2f){0.f, 0.f};

    const float* nbp = neibs + ((size_t)b * Nv + n0) * Fv + f;
    const float* dp  = dsum  + ((size_t)b * Nv + n0) * Cv + c0;

    #pragma unroll 2
    for (int n = 0; n < NCH; ++n) {
        const float nbv = nbp[(size_t)n * Fv];
        const v2f nb2 = {nbv, nbv};
        const v2f* dp2 = reinterpret_cast<const v2f*>(dp + (size_t)n * Cv);
        #pragma unroll
        for (int k = 0; k < CQ / 2; ++k)
            acc2[k] += dp2[k] * nb2;   // hoped: v_pk_fma_f32
    }

    if (ATOMIC) {
        float* op = dst + ((size_t)b * Cv + c0) * Fv + f;
        #pragma unroll
        for (int k = 0; k < CQ / 2; ++k) {
            atomicAdd(op + (size_t)(2 * k)     * Fv, acc2[k].x);
            atomicAdd(op + (size_t)(2 * k + 1) * Fv, acc2[k].y);
        }
    } else {
        float* op = dst + (size_t)nc * OUT_FLOATS + ((size_t)b * Cv + c0) * Fv + f;
        #pragma unroll
        for (int k = 0; k < CQ / 2; ++k) {
            op[(size_t)(2 * k)     * Fv] = acc2[k].x;
            op[(size_t)(2 * k + 1) * Fv] = acc2[k].y;
        }
    }
}

// out[i] = sum_nc partials[nc][i] — pure-BW fold of the 16 partial buffers.
__global__ __launch_bounds__(256)
void reduce_kernel(const float* __restrict__ partials, float* __restrict__ out)
{
    const size_t i = ((size_t)blockIdx.x * 256 + threadIdx.x) * 4;
    float4 s = {0.f, 0.f, 0.f, 0.f};
    #pragma unroll
    for (int nc = 0; nc < NPART; ++nc) {
        const float4 p = *reinterpret_cast<const float4*>(partials + nc * OUT_FLOATS + i);
        s.x += p.x; s.y += p.y; s.z += p.z; s.w += p.w;
    }
    *reinterpret_cast<float4*>(out + i) = s;
}

extern "C" void kernel_launch(void* const* d_in, const int* in_sizes, int n_in,
                              void* d_out, int out_size, void* d_ws, size_t ws_size,
                              hipStream_t stream)
{
    const float* amps   = (const float*)d_in[0];
    const float* neibs  = (const float*)d_in[1];
    const float* coins  = (const float*)d_in[2];
    const int*   swap_a = (const int*)d_in[3];
    const int*   swap_b = (const int*)d_in[4];
    float* out  = (float*)d_out;
    float* dsum = (float*)d_ws;        // [0, 8 MiB)

    // Try to opt in to 128 KB dynamic LDS. Host-side module state, not a
    // stream op -> graph-capture-safe; same result every call. Fall back to
    // the 64 KB walk variant if refused so the launch never fails.
    hipError_t attr_ok = hipFuncSetAttribute(
        reinterpret_cast<const void*>(&walk_kernel<BIG_TILE, BIG_LN, BIG_NT>),
        hipFuncAttributeMaxDynamicSharedMemorySize, (int)BIG_LDS);

    // Partials path (no atomics) if workspace is big enough; ws_size is
    // call-invariant -> branch is graph-consistent.
    const bool use_partials = (ws_size >= DSUM_BYTES + PART_BYTES);
    float* partials = (float*)((char*)d_ws + DSUM_BYTES);  // [8, 24 MiB)

    if (!use_partials) {
        // atomic path accumulates into out -> zero it (re-poisoned to 0xAA)
        hipMemsetAsync(d_out, 0, OUT_FLOATS * sizeof(float), stream);
    }

    if (attr_ok == hipSuccess) {
        walk_kernel<BIG_TILE, BIG_LN, BIG_NT>
            <<<Bv * BIG_NT * 4, BIG_LN * 8, BIG_LDS, stream>>>(
                amps, coins, swap_a, swap_b, dsum);
    } else {
        walk_kernel<SM_TILE, SM_LN, SM_NT>
            <<<Bv * SM_NT * 4, SM_LN * 8, SM_LDS, stream>>>(
                amps, coins, swap_a, swap_b, dsum);
    }

    const int quant_grid = Bv * (Cv / CQ) * NPART;   // 512
    if (use_partials) {
        quant_kernel<false><<<quant_grid, 256, 0, stream>>>(dsum, neibs, partials);
        reduce_kernel<<<(int)(OUT_FLOATS / 4 / 256), 256, 0, stream>>>(partials, out);
    } else {
        quant_kernel<true><<<quant_grid, 256, 0, stream>>>(dsum, neibs, out);
    }
}

// Round 10
// 197.659 us; speedup vs baseline: 1.0365x; 1.0365x over previous
//
#include <hip/hip_runtime.h>

// Problem constants (match reference setup_inputs()).
#define Bv 8
#define Nv 2048
#define Dv 8
#define Cv 128
#define Fv 256
#define Tv 4

// ---- walk config: 3 resident blocks/CU, balanced grid ----
#define CC    16               // c per walk block (4 float4 lanes)
#define TILE  64               // owned n per block
#define HALO  16               // 4 steps * max offset 4
#define LN    96               // loaded n; NOT pow2 -> arithmetic wrap in prologue
#define RS    132              // LDS row stride in floats (132%32=4 -> banks spread)
#define NT    32               // 2048/64 tiles, exact
// LDS = 96*132*4 = 50688 B -> 3 blocks/CU (152 KB of 160). grid = 8*32*8 = 2048 = 8/CU.

// Fused T-step walk. Each block: one b, 64 owned n (+16 halo each side = 96
// loaded), 16 c. Thread: one n-slot (nl=tid>>2), float4 of c (ci4=tid&3),
// all 8 d in registers. Exchange via LDS b128 both sides at the structural
// 8-lanes/bank-quad floor (row stride 132: publish quad=(nl+ci4+4e)%8,
// gather quad=(nl+off_d+4*sb_d+ci4)%8 with off_d,sb_d wave-constant ->
// exactly 8 lanes per quad on both sides).
// Valid region after step t: [4t, LN-4t); owned [16,80) = the T=4 cone.
__global__ __launch_bounds__(LN * 4, 4)
void walk_kernel(const float* __restrict__ amps0,
                 const float* __restrict__ coins,
                 const int* __restrict__ swap_a,
                 const int* __restrict__ swap_b,
                 float* __restrict__ dsum)
{
    __shared__ float abuf[LN * RS];        // 50688 B

    const int bid  = blockIdx.x;
    const int b    = bid >> 8;             // 256 blocks per batch
    const int rem  = bid & 255;
    const int tile = rem >> 3;             // 0..31
    const int c0   = (rem & 7) * CC;       // 8 c-chunks of 16

    const int tid = threadIdx.x;
    const int ci4 = tid & 3;               // c = c0 + ci4*4 + 0..3
    const int nl  = tid >> 2;              // 0..95 local n slot

    const int n_load_start = tile * TILE - HALO;    // may be negative (mod N)
    const int ng = (n_load_start + nl) & (Nv - 1);  // global n of this slot

    float4 amp[Dv];     // per-thread amplitude state (8 d x 4 c)
    int    idx[Dv];     // LDS gather offsets (t-invariant, float index)

    // ---- load initial amplitudes (float4, coalesced 64B segments) ----
    {
        const float* srcf = amps0 + ((size_t)(b * Nv + ng) * Dv) * Cv + c0 + ci4 * 4;
        #pragma unroll
        for (int dd = 0; dd < Dv; ++dd)
            amp[dd] = *reinterpret_cast<const float4*>(srcf + (size_t)dd * Cv);
    }

    // ---- precompute gather offsets (t-invariant); LN=96 arithmetic wrap ----
    {
        const int* pa = swap_a + (size_t)(b * Nv + ng) * Dv;
        const int* pb = swap_b + (size_t)(b * Nv + ng) * Dv;
        #pragma unroll
        for (int dd = 0; dd < Dv; ++dd) {
            const int sa = pa[dd];
            const int sb = pb[dd];
            int s1 = sa - n_load_start;          // (-2032, 2064)
            if (s1 < 0)   s1 += Nv;              // [0, 2N)
            if (s1 >= Nv) s1 -= Nv;              // [0, N): mod-N offset in window
            if (s1 >= LN) s1 &= 63;              // halo-edge garbage -> any in-range
            idx[dd] = s1 * RS + sb * CC + ci4 * 4;
        }
    }

    // ---- coin coefficients: hoisted structure check (one-time) ----
    // Grover: cm = wd*I + wo*(J-I). Uniform addresses -> scalar loads.
    float wdv[Tv], wov[Tv];
    bool uni = true;
    #pragma unroll
    for (int tt = 0; tt < Tv; ++tt) {
        const float* cm = coins + tt * Dv * Dv;
        wdv[tt] = cm[0];
        wov[tt] = cm[1];
        #pragma unroll
        for (int i = 0; i < Dv; ++i)
            #pragma unroll
            for (int j = 0; j < Dv; ++j)
                uni = uni && (cm[i * Dv + j] == ((i == j) ? wdv[tt] : wov[tt]));
    }

    #pragma unroll
    for (int t = 0; t < Tv; ++t) {
        float4 a[Dv];
        if (uni) {
            // a[e] = fma(dw, amp[e], wo*s),  s = sum_d amp[d]
            const float wo = wov[t];
            const float dw = wdv[t] - wo;
            float4 s = amp[0];
            #pragma unroll
            for (int dd = 1; dd < Dv; ++dd) {
                s.x += amp[dd].x; s.y += amp[dd].y;
                s.z += amp[dd].z; s.w += amp[dd].w;
            }
            const float4 ws = {wo * s.x, wo * s.y, wo * s.z, wo * s.w};
            #pragma unroll
            for (int e = 0; e < Dv; ++e) {
                a[e].x = fmaf(dw, amp[e].x, ws.x);
                a[e].y = fmaf(dw, amp[e].y, ws.y);
                a[e].z = fmaf(dw, amp[e].z, ws.z);
                a[e].w = fmaf(dw, amp[e].w, ws.w);
            }
        } else {
            const float* cm = coins + t * Dv * Dv;
            #pragma unroll
            for (int e = 0; e < Dv; ++e) { a[e].x = a[e].y = a[e].z = a[e].w = 0.f; }
            #pragma unroll
            for (int dd = 0; dd < Dv; ++dd) {
                #pragma unroll
                for (int e = 0; e < Dv; ++e) {
                    const float w = cm[dd * Dv + e];
                    a[e].x += amp[dd].x * w;
                    a[e].y += amp[dd].y * w;
                    a[e].z += amp[dd].z * w;
                    a[e].w += amp[dd].w * w;
                }
            }
        }

        // publish: 8 x ds_write_b128 (structural-floor banking)
        {
            float* base = abuf + nl * RS + ci4 * 4;
            #pragma unroll
            for (int e = 0; e < Dv; ++e)
                *reinterpret_cast<float4*>(base + e * CC) = a[e];
        }
        __syncthreads();
        // gather: 8 x ds_read_b128
        #pragma unroll
        for (int dd = 0; dd < Dv; ++dd)
            amp[dd] = *reinterpret_cast<const float4*>(&abuf[idx[dd]]);
        __syncthreads();
    }

    // d[b,n,c] = sum_d amps^2, owned region only (float4 store)
    if (nl >= HALO && nl < HALO + TILE) {
        float4 s;
        s.x = s.y = s.z = s.w = 0.f;
        #pragma unroll
        for (int dd = 0; dd < Dv; ++dd) {
            s.x += amp[dd].x * amp[dd].x;
            s.y += amp[dd].y * amp[dd].y;
            s.z += amp[dd].z * amp[dd].z;
            s.w += amp[dd].w * amp[dd].w;
        }
        *reinterpret_cast<float4*>(dsum + (size_t)(b * Nv + ng) * Cv + c0 + ci4 * 4) = s;
    }
}

// ---- quant: register-tiled GEMM, zero atomics on every path ----
// out[b,c,f] = sum_n d[b,n,c] * neibs[b,n,f]  ==  per-b GEMM [C x N]*[N x F].
// Block: (b, c-tile 64, f-tile 64, n-chunk). 256 threads; thread (tc,tf) owns
// a 4c x 4f register tile (8 v2f accumulators -> v_pk_fma_f32).
// Loads: dv broadcast across tf (4 distinct 16B lines/wave, one 64B segment);
// nv 16 consecutive lines/wave (256B segment). No LDS, no sync, no atomics.
// NSPL_>1: disjoint partials per n-chunk, folded by reduce_kernel.
// NSPL_==1: direct store to out (small-ws fallback, still atomic-free).
#define NSPL  8
constexpr size_t OUT_FLOATS = (size_t)Bv * Cv * Fv;        // 262144 (1 MiB)
constexpr size_t DSUM_BYTES = (size_t)Bv * Nv * Cv * 4;    // 8 MiB
constexpr size_t PART_BYTES = (size_t)NSPL * OUT_FLOATS * 4; // 8 MiB

typedef float v2f __attribute__((ext_vector_type(2)));

template<int NSPL_>
__global__ __launch_bounds__(256)
void quant_kernel(const float* __restrict__ dsum,
                  const float* __restrict__ neibs,
                  float* __restrict__ dst)   // partials (NSPL_>1) or out (==1)
{
    const int bid = blockIdx.x;
    const int nc  = bid % NSPL_;
    int r = bid / NSPL_;
    const int ft = r & 3;  r >>= 2;          // 4 f-tiles of 64
    const int ct = r & 1;  r >>= 1;          // 2 c-tiles of 64
    const int b  = r;                        // 8 batches

    const int tid = threadIdx.x;
    const int tf  = tid & 15;
    const int tc  = tid >> 4;

    const int c0  = ct * 64 + tc * 4;
    const int f0  = ft * 64 + tf * 4;
    const int n0  = nc * (Nv / NSPL_);
    const int nch = Nv / NSPL_;

    const float* dg = dsum  + ((size_t)b * Nv + n0) * Cv + c0;
    const float* ng = neibs + ((size_t)b * Nv + n0) * Fv + f0;

    v2f acc[4][2];
    #pragma unroll
    for (int i = 0; i < 4; ++i) {
        acc[i][0] = (v2f){0.f, 0.f};
        acc[i][1] = (v2f){0.f, 0.f};
    }

    #pragma unroll 4
    for (int k = 0; k < nch; ++k) {
        const float4 dv = *reinterpret_cast<const float4*>(dg + (size_t)k * Cv);
        const float4 nv = *reinterpret_cast<const float4*>(ng + (size_t)k * Fv);
        const v2f nb0 = {nv.x, nv.y};
        const v2f nb1 = {nv.z, nv.w};
        acc[0][0] += nb0 * dv.x;  acc[0][1] += nb1 * dv.x;
        acc[1][0] += nb0 * dv.y;  acc[1][1] += nb1 * dv.y;
        acc[2][0] += nb0 * dv.z;  acc[2][1] += nb1 * dv.z;
        acc[3][0] += nb0 * dv.w;  acc[3][1] += nb1 * dv.w;
    }

    float* op = dst + (size_t)nc * OUT_FLOATS + ((size_t)b * Cv + c0) * Fv + f0;
    #pragma unroll
    for (int i = 0; i < 4; ++i) {
        const float4 v = {acc[i][0].x, acc[i][0].y, acc[i][1].x, acc[i][1].y};
        *reinterpret_cast<float4*>(op + (size_t)i * Fv) = v;
    }
}

// out[i] = sum_nc partials[nc][i] — pure-BW fold of the NSPL partial buffers.
__global__ __launch_bounds__(256)
void reduce_kernel(const float* __restrict__ partials, float* __restrict__ out)
{
    const size_t i = ((size_t)blockIdx.x * 256 + threadIdx.x) * 4;
    float4 s = {0.f, 0.f, 0.f, 0.f};
    #pragma unroll
    for (int nc = 0; nc < NSPL; ++nc) {
        const float4 p = *reinterpret_cast<const float4*>(partials + nc * OUT_FLOATS + i);
        s.x += p.x; s.y += p.y; s.z += p.z; s.w += p.w;
    }
    *reinterpret_cast<float4*>(out + i) = s;
}

extern "C" void kernel_launch(void* const* d_in, const int* in_sizes, int n_in,
                              void* d_out, int out_size, void* d_ws, size_t ws_size,
                              hipStream_t stream)
{
    const float* amps   = (const float*)d_in[0];
    const float* neibs  = (const float*)d_in[1];
    const float* coins  = (const float*)d_in[2];
    const int*   swap_a = (const int*)d_in[3];
    const int*   swap_b = (const int*)d_in[4];
    float* out  = (float*)d_out;
    float* dsum = (float*)d_ws;        // [0, 8 MiB)

    walk_kernel<<<Bv * NT * (Cv / CC), LN * 4, 0, stream>>>(
        amps, coins, swap_a, swap_b, dsum);

    // ws_size is call-invariant -> branch is graph-consistent.
    const bool use_partials = (ws_size >= DSUM_BYTES + PART_BYTES);
    float* partials = (float*)((char*)d_ws + DSUM_BYTES);  // [8, 16 MiB)

    if (use_partials) {
        quant_kernel<NSPL><<<Bv * 2 * 4 * NSPL, 256, 0, stream>>>(dsum, neibs, partials);
        reduce_kernel<<<(int)(OUT_FLOATS / 4 / 256), 256, 0, stream>>>(partials, out);
    } else {
        quant_kernel<1><<<Bv * 2 * 4, 256, 0, stream>>>(dsum, neibs, out);
    }
}